// Round 1
// baseline (1578.339 us; speedup 1.0000x reference)
//
#include <hip/hip_runtime.h>

#define NN 50000
#define EE 800000
#define FF 128
#define OO 64
#define EPSF 1e-5f

// ---- edge-index access: handles both int32 and int64 serialized layouts ----
__device__ __forceinline__ int eidx(const void* ei, long long pos, int f64) {
  if (f64) return (int)((const long long*)ei)[pos];
  return ((const int*)ei)[pos];
}

__global__ void k_detect(const void* ei, int* flag) {
  if (threadIdx.x == 0 && blockIdx.x == 0) {
    const int* p = (const int*)ei;
    int any = 0;
    for (int i = 1; i < 128; i += 2) any |= p[i];  // high words all 0 <=> int64
    *flag = (any == 0) ? 1 : 0;
  }
}

__global__ void k_deg_init(float* deg) {
  int i = blockIdx.x * blockDim.x + threadIdx.x;
  if (i < NN) deg[i] = 1.0f;  // self-loop
}

__global__ void k_deg_edges(const void* ei, const int* __restrict__ flag, float* deg) {
  int f64 = *flag;
  int stride = gridDim.x * blockDim.x;
  for (int e = blockIdx.x * blockDim.x + threadIdx.x; e < EE; e += stride) {
    int d = eidx(ei, (long long)EE + e, f64);
    atomicAdd(&deg[d], 1.0f);
  }
}

__global__ void k_rsqrt(float* deg) {
  int i = blockIdx.x * blockDim.x + threadIdx.x;
  if (i < NN) deg[i] = rsqrtf(deg[i]);  // deg >= 1 always (self-loops)
}

// T[r,c] = sum_k X[r,k] * W[k,c]   (W is 128x128, cached in LDS)
__global__ __launch_bounds__(256) void k_gemm128(const float* __restrict__ X,
                                                 const float* __restrict__ W,
                                                 float* __restrict__ T) {
  __shared__ float Ws[FF * FF];  // 64 KB -> 2 blocks/CU
  for (int i = threadIdx.x; i < FF * FF; i += 256) Ws[i] = W[i];
  __syncthreads();
  int c = threadIdx.x & 127;
  int half = threadIdx.x >> 7;  // 2 rows per block-iter
  for (int r = blockIdx.x * 2 + half; r < NN; r += gridDim.x * 2) {
    const float* xr = X + (size_t)r * FF;
    float acc = 0.f;
#pragma unroll
    for (int k = 0; k < FF; ++k) acc = fmaf(xr[k], Ws[k * FF + c], acc);
    T[(size_t)r * FF + c] = acc;
  }
}

// agg[i,:] = dis[i]^2 * feat[i,:]   (self-loop term, also zero-initializes agg)
__global__ void k_self(const float* __restrict__ dis, const float* __restrict__ feat,
                       float* __restrict__ agg) {
  int stride = gridDim.x * blockDim.x;
  int total = NN * (FF / 4);
  const float4* f4 = (const float4*)feat;
  float4* a4 = (float4*)agg;
  for (int t = blockIdx.x * blockDim.x + threadIdx.x; t < total; t += stride) {
    int i = t >> 5;  // /(FF/4)
    float w = dis[i]; w = w * w;
    float4 v = f4[t];
    v.x *= w; v.y *= w; v.z *= w; v.w *= w;
    a4[t] = v;
  }
}

// one 64-lane wave per edge: agg[dst,:] += dis[src]*dis[dst] * feat[src,:]
__global__ __launch_bounds__(256) void k_spmm_edges(const void* ei, const int* __restrict__ flag,
                                                    const float* __restrict__ dis,
                                                    const float* __restrict__ feat,
                                                    float* __restrict__ agg) {
  int f64 = *flag;
  int gw = (blockIdx.x * blockDim.x + threadIdx.x) >> 6;
  int lane = threadIdx.x & 63;
  int nw = (gridDim.x * blockDim.x) >> 6;
  for (int e = gw; e < EE; e += nw) {
    int s = eidx(ei, e, f64);
    int d = eidx(ei, (long long)EE + e, f64);
    float nrm = dis[s] * dis[d];
    const float2* fs = (const float2*)(feat + (size_t)s * FF);
    float* ad = agg + (size_t)d * FF;
    float2 v = fs[lane];
    atomicAdd(&ad[2 * lane],     nrm * v.x);
    atomicAdd(&ad[2 * lane + 1], nrm * v.y);
  }
}

// h[i,:] = LN(relu(agg[i,:] + b1)) * gamma + beta   (one wave per node)
__global__ __launch_bounds__(256) void k_relu_ln(const float* __restrict__ agg,
                                                 const float* __restrict__ b1,
                                                 const float* __restrict__ gamma,
                                                 const float* __restrict__ beta,
                                                 float* __restrict__ h) {
  int node = blockIdx.x * 4 + (threadIdx.x >> 6);
  int lane = threadIdx.x & 63;
  if (node >= NN) return;
  const float2* ar = (const float2*)(agg + (size_t)node * FF);
  float2 v = ar[lane];
  float2 bb = ((const float2*)b1)[lane];
  float a0 = fmaxf(v.x + bb.x, 0.f);
  float a1 = fmaxf(v.y + bb.y, 0.f);
  float s = a0 + a1;
  float sq = a0 * a0 + a1 * a1;
#pragma unroll
  for (int m = 1; m < 64; m <<= 1) {
    s += __shfl_xor(s, m);
    sq += __shfl_xor(sq, m);
  }
  float mean = s * (1.f / 128.f);
  float var = sq * (1.f / 128.f) - mean * mean;
  float rstd = rsqrtf(var + EPSF);
  float2 g = ((const float2*)gamma)[lane];
  float2 be = ((const float2*)beta)[lane];
  float2 o;
  o.x = (a0 - mean) * rstd * g.x + be.x;
  o.y = (a1 - mean) * rstd * g.y + be.y;
  ((float2*)(h + (size_t)node * FF))[lane] = o;
}

// out[0:N*64)    = A @ Wmu + bmu
// out[N*64:2N*64)= A @ Wlv + blv     (both W's in LDS; 128 outputs x 2 rows per block-iter)
__global__ __launch_bounds__(256) void k_gemm_out(const float* __restrict__ A,
                                                  const float* __restrict__ Wmu,
                                                  const float* __restrict__ bmu,
                                                  const float* __restrict__ Wlv,
                                                  const float* __restrict__ blv,
                                                  float* __restrict__ out) {
  __shared__ float Ws[2][FF * OO];  // 2 x 32 KB
  for (int i = threadIdx.x; i < FF * OO; i += 256) { Ws[0][i] = Wmu[i]; Ws[1][i] = Wlv[i]; }
  __syncthreads();
  int c = threadIdx.x & 63;
  int sel = (threadIdx.x >> 6) & 1;
  int half = threadIdx.x >> 7;
  const float* bias = sel ? blv : bmu;
  for (int r = blockIdx.x * 2 + half; r < NN; r += gridDim.x * 2) {
    const float* ar = A + (size_t)r * FF;
    float acc = 0.f;
#pragma unroll
    for (int k = 0; k < FF; ++k) acc = fmaf(ar[k], Ws[sel][k * OO + c], acc);
    acc += bias[c];
    out[(size_t)sel * NN * OO + (size_t)r * OO + c] = acc;
  }
}

extern "C" void kernel_launch(void* const* d_in, const int* in_sizes, int n_in,
                              void* d_out, int out_size, void* d_ws, size_t ws_size,
                              hipStream_t stream) {
  const float* x     = (const float*)d_in[0];
  const void*  ei    = d_in[1];
  const float* W1    = (const float*)d_in[2];
  const float* b1    = (const float*)d_in[3];
  const float* gamma = (const float*)d_in[4];
  const float* beta  = (const float*)d_in[5];
  const float* Wmu   = (const float*)d_in[6];
  const float* bmu   = (const float*)d_in[7];
  const float* Wlv   = (const float*)d_in[8];
  const float* blv   = (const float*)d_in[9];
  float* out = (float*)d_out;

  // workspace layout (floats): [flag pad 64][dis N][t N*128][agg N*128][h N*128]  ~77 MB
  float* ws  = (float*)d_ws;
  int*   flag = (int*)d_ws;
  float* dis = ws + 64;
  float* t   = dis + NN;              // x@W1; later reused as agg2
  float* agg = t + (size_t)NN * FF;   // conv1 aggregation
  float* h   = agg + (size_t)NN * FF; // post ReLU+LN

  k_detect<<<1, 64, 0, stream>>>(ei, flag);
  k_deg_init<<<(NN + 255) / 256, 256, 0, stream>>>(dis);
  k_deg_edges<<<1024, 256, 0, stream>>>(ei, flag, dis);
  k_rsqrt<<<(NN + 255) / 256, 256, 0, stream>>>(dis);

  k_gemm128<<<512, 256, 0, stream>>>(x, W1, t);            // t = x@W1
  k_self<<<2048, 256, 0, stream>>>(dis, t, agg);           // agg = D^-1 t (self-loops)
  k_spmm_edges<<<2048, 256, 0, stream>>>(ei, flag, dis, t, agg);
  k_relu_ln<<<(NN + 3) / 4, 256, 0, stream>>>(agg, b1, gamma, beta, h);
  k_self<<<2048, 256, 0, stream>>>(dis, h, t);             // agg2 (reuse t)
  k_spmm_edges<<<2048, 256, 0, stream>>>(ei, flag, dis, h, t);
  k_gemm_out<<<512, 256, 0, stream>>>(t, Wmu, bmu, Wlv, blv, out);
}

// Round 2
// 504.275 us; speedup vs baseline: 3.1299x; 3.1299x over previous
//
#include <hip/hip_runtime.h>

#define NN 50000
#define EE 800000
#define FF 128
#define OO 64
#define EPSF 1e-5f
#define SCAN_T 1024
#define SCAN_CH 49  // ceil(NN / SCAN_T)

// ---- edge-index access: handles both int32 and int64 serialized layouts ----
__device__ __forceinline__ int eidx(const void* ei, long long pos, int f64) {
  if (f64) return (int)((const long long*)ei)[pos];
  return ((const int*)ei)[pos];
}

__global__ void k_detect(const void* ei, int* flag) {
  if (threadIdx.x == 0 && blockIdx.x == 0) {
    const int* p = (const int*)ei;
    int any = 0;
    for (int i = 1; i < 128; i += 2) any |= p[i];  // high words all 0 <=> int64
    *flag = (any == 0) ? 1 : 0;
  }
}

__global__ void k_cnt_init(int* cnt) {
  int i = blockIdx.x * blockDim.x + threadIdx.x;
  if (i < NN) cnt[i] = 0;
}

__global__ void k_deg_edges(const void* ei, const int* __restrict__ flag, int* cnt) {
  int f64 = *flag;
  int stride = gridDim.x * blockDim.x;
  for (int e = blockIdx.x * blockDim.x + threadIdx.x; e < EE; e += stride) {
    int d = eidx(ei, (long long)EE + e, f64);
    atomicAdd(&cnt[d], 1);
  }
}

__global__ void k_dis(const int* __restrict__ cnt, float* dis) {
  int i = blockIdx.x * blockDim.x + threadIdx.x;
  if (i < NN) dis[i] = rsqrtf((float)(cnt[i] + 1));  // +1 self-loop, always > 0
}

// single-block exclusive scan of cnt -> rowptr (and pos = rowptr copy)
__global__ __launch_bounds__(SCAN_T) void k_scan(const int* __restrict__ cnt,
                                                 int* __restrict__ rowptr,
                                                 int* __restrict__ pos) {
  __shared__ int sums[SCAN_T];
  int tid = threadIdx.x;
  int base = tid * SCAN_CH;
  int vals[SCAN_CH];
  int local = 0;
#pragma unroll
  for (int j = 0; j < SCAN_CH; ++j) {
    int idx = base + j;
    int v = (idx < NN) ? cnt[idx] : 0;
    vals[j] = v;
    local += v;
  }
  sums[tid] = local;
  __syncthreads();
  for (int off = 1; off < SCAN_T; off <<= 1) {
    int v = (tid >= off) ? sums[tid - off] : 0;
    __syncthreads();
    sums[tid] += v;
    __syncthreads();
  }
  int run = sums[tid] - local;  // exclusive prefix of this chunk
#pragma unroll
  for (int j = 0; j < SCAN_CH; ++j) {
    int idx = base + j;
    if (idx < NN) { rowptr[idx] = run; pos[idx] = run; }
    run += vals[j];
  }
  if (tid == SCAN_T - 1) rowptr[NN] = run;
}

// counting-sort scatter: col[p] = src, w[p] = dis[src]*dis[dst], sorted by dst
__global__ void k_scatter(const void* ei, const int* __restrict__ flag,
                          const float* __restrict__ dis,
                          int* __restrict__ pos, int* __restrict__ col,
                          float* __restrict__ w) {
  int f64 = *flag;
  int stride = gridDim.x * blockDim.x;
  for (int e = blockIdx.x * blockDim.x + threadIdx.x; e < EE; e += stride) {
    int s = eidx(ei, e, f64);
    int d = eidx(ei, (long long)EE + e, f64);
    int p = atomicAdd(&pos[d], 1);
    col[p] = s;
    w[p] = dis[s] * dis[d];
  }
}

// T[r,c] = sum_k X[r,k] * W[k,c]   (W is 128x128, cached in LDS)
__global__ __launch_bounds__(256) void k_gemm128(const float* __restrict__ X,
                                                 const float* __restrict__ W,
                                                 float* __restrict__ T) {
  __shared__ float Ws[FF * FF];  // 64 KB
  for (int i = threadIdx.x; i < FF * FF; i += 256) Ws[i] = W[i];
  __syncthreads();
  int c = threadIdx.x & 127;
  int half = threadIdx.x >> 7;
  for (int r = blockIdx.x * 2 + half; r < NN; r += gridDim.x * 2) {
    const float* xr = X + (size_t)r * FF;
    float acc = 0.f;
#pragma unroll
    for (int k = 0; k < FF; ++k) acc = fmaf(xr[k], Ws[k * FF + c], acc);
    T[(size_t)r * FF + c] = acc;
  }
}

// one wave per node: acc = dis[i]^2*feat[i] + sum_e w[e]*feat[col[e]]
// LN=1: fused bias+ReLU+LayerNorm epilogue (conv1); LN=0: raw write (conv2)
template <int LN>
__global__ __launch_bounds__(256) void k_gather(const int* __restrict__ rowptr,
                                                const int* __restrict__ col,
                                                const float* __restrict__ w,
                                                const float* __restrict__ dis,
                                                const float* __restrict__ feat,
                                                const float* __restrict__ b1,
                                                const float* __restrict__ gamma,
                                                const float* __restrict__ beta,
                                                float* __restrict__ outp) {
  int node = blockIdx.x * 4 + (threadIdx.x >> 6);
  if (node >= NN) return;
  int lane = threadIdx.x & 63;
  float di = dis[node];
  float2 v = ((const float2*)(feat + (size_t)node * FF))[lane];
  float sw = di * di;
  float ax = sw * v.x, ay = sw * v.y;
  int e = rowptr[node], end = rowptr[node + 1];
  for (; e + 1 < end; e += 2) {
    int s0 = col[e], s1 = col[e + 1];
    float w0 = w[e], w1 = w[e + 1];
    float2 v0 = ((const float2*)(feat + (size_t)s0 * FF))[lane];
    float2 v1 = ((const float2*)(feat + (size_t)s1 * FF))[lane];
    ax = fmaf(w0, v0.x, ax); ay = fmaf(w0, v0.y, ay);
    ax = fmaf(w1, v1.x, ax); ay = fmaf(w1, v1.y, ay);
  }
  if (e < end) {
    int s0 = col[e];
    float w0 = w[e];
    float2 v0 = ((const float2*)(feat + (size_t)s0 * FF))[lane];
    ax = fmaf(w0, v0.x, ax); ay = fmaf(w0, v0.y, ay);
  }
  float2 o;
  if (LN) {
    float2 bb = ((const float2*)b1)[lane];
    float a0 = fmaxf(ax + bb.x, 0.f);
    float a1 = fmaxf(ay + bb.y, 0.f);
    float s = a0 + a1, sq = a0 * a0 + a1 * a1;
#pragma unroll
    for (int m = 1; m < 64; m <<= 1) {
      s += __shfl_xor(s, m);
      sq += __shfl_xor(sq, m);
    }
    float mean = s * (1.f / 128.f);
    float var = sq * (1.f / 128.f) - mean * mean;
    float rstd = rsqrtf(var + EPSF);
    float2 g = ((const float2*)gamma)[lane];
    float2 be = ((const float2*)beta)[lane];
    o.x = (a0 - mean) * rstd * g.x + be.x;
    o.y = (a1 - mean) * rstd * g.y + be.y;
  } else {
    o.x = ax; o.y = ay;
  }
  ((float2*)(outp + (size_t)node * FF))[lane] = o;
}

// out[0:N*64) = A@Wmu + bmu ; out[N*64:2N*64) = A@Wlv + blv
__global__ __launch_bounds__(256) void k_gemm_out(const float* __restrict__ A,
                                                  const float* __restrict__ Wmu,
                                                  const float* __restrict__ bmu,
                                                  const float* __restrict__ Wlv,
                                                  const float* __restrict__ blv,
                                                  float* __restrict__ out) {
  __shared__ float Ws[2][FF * OO];
  for (int i = threadIdx.x; i < FF * OO; i += 256) { Ws[0][i] = Wmu[i]; Ws[1][i] = Wlv[i]; }
  __syncthreads();
  int c = threadIdx.x & 63;
  int sel = (threadIdx.x >> 6) & 1;
  int half = threadIdx.x >> 7;
  const float* bias = sel ? blv : bmu;
  for (int r = blockIdx.x * 2 + half; r < NN; r += gridDim.x * 2) {
    const float* ar = A + (size_t)r * FF;
    float acc = 0.f;
#pragma unroll
    for (int k = 0; k < FF; ++k) acc = fmaf(ar[k], Ws[sel][k * OO + c], acc);
    acc += bias[c];
    out[(size_t)sel * NN * OO + (size_t)r * OO + c] = acc;
  }
}

extern "C" void kernel_launch(void* const* d_in, const int* in_sizes, int n_in,
                              void* d_out, int out_size, void* d_ws, size_t ws_size,
                              hipStream_t stream) {
  const float* x     = (const float*)d_in[0];
  const void*  ei    = d_in[1];
  const float* W1    = (const float*)d_in[2];
  const float* b1    = (const float*)d_in[3];
  const float* gamma = (const float*)d_in[4];
  const float* beta  = (const float*)d_in[5];
  const float* Wmu   = (const float*)d_in[6];
  const float* bmu   = (const float*)d_in[7];
  const float* Wlv   = (const float*)d_in[8];
  const float* blv   = (const float*)d_in[9];
  float* out = (float*)d_out;

  // workspace layout (4B words), ~58.4 MB total:
  // [flag 64][cnt N][rowptr N+16][pos N][dis N][col E][w E][t N*128][h N*128]
  int*   flag   = (int*)d_ws;
  int*   cnt    = flag + 64;
  int*   rowptr = cnt + NN;
  int*   pos    = rowptr + (NN + 16);
  float* dis    = (float*)(pos + NN);
  int*   col    = (int*)(dis + NN);
  float* w      = (float*)(col + EE);
  float* t      = w + EE;               // x@W1; reused as agg2 for conv2
  float* h      = t + (size_t)NN * FF;  // post ReLU+LN

  k_detect<<<1, 64, 0, stream>>>(ei, flag);
  k_cnt_init<<<(NN + 255) / 256, 256, 0, stream>>>(cnt);
  k_deg_edges<<<1024, 256, 0, stream>>>(ei, flag, cnt);
  k_dis<<<(NN + 255) / 256, 256, 0, stream>>>(cnt, dis);
  k_scan<<<1, SCAN_T, 0, stream>>>(cnt, rowptr, pos);
  k_scatter<<<1024, 256, 0, stream>>>(ei, flag, dis, pos, col, w);

  k_gemm128<<<512, 256, 0, stream>>>(x, W1, t);  // t = x@W1
  k_gather<1><<<(NN + 3) / 4, 256, 0, stream>>>(rowptr, col, w, dis, t, b1, gamma, beta, h);
  k_gather<0><<<(NN + 3) / 4, 256, 0, stream>>>(rowptr, col, w, dis, h, b1, gamma, beta, t);
  k_gemm_out<<<512, 256, 0, stream>>>(t, Wmu, bmu, Wlv, blv, out);
}

// Round 3
// 312.261 us; speedup vs baseline: 5.0545x; 1.6149x over previous
//
#include <hip/hip_runtime.h>

#define NN 50000
#define EE 800000
#define FF 128
#define OO 64
#define EPSF 1e-5f
#define SCAN_T 1024
#define SCAN_CH 49  // ceil(NN / SCAN_T)

typedef unsigned int uint;
typedef unsigned short ushort;

// ---- bf16 helpers (RTNE pack, cheap unpack) ----
__device__ __forceinline__ float bflo(uint v) { return __uint_as_float(v << 16); }
__device__ __forceinline__ float bfhi(uint v) { return __uint_as_float(v & 0xFFFF0000u); }
__device__ __forceinline__ uint f2bf(float f) {
  uint b = __float_as_uint(f);
  return (b + 0x7FFFu + ((b >> 16) & 1u)) >> 16;
}
__device__ __forceinline__ uint pack2(float x, float y) { return f2bf(x) | (f2bf(y) << 16); }

// ---- edge-index access: handles both int32 and int64 serialized layouts ----
__device__ __forceinline__ int eidx(const void* ei, long long pos, int f64) {
  if (f64) return (int)((const long long*)ei)[pos];
  return ((const int*)ei)[pos];
}

__global__ void k_detect(const void* ei, int* flag) {
  if (threadIdx.x == 0 && blockIdx.x == 0) {
    const int* p = (const int*)ei;
    int any = 0;
    for (int i = 1; i < 128; i += 2) any |= p[i];  // high words all 0 <=> int64
    *flag = (any == 0) ? 1 : 0;
  }
}

__global__ void k_cnt_init(int* cnt) {
  int i = blockIdx.x * blockDim.x + threadIdx.x;
  if (i < NN) cnt[i] = 0;
}

__global__ void k_deg_edges(const void* ei, const int* __restrict__ flag, int* cnt) {
  int f64 = *flag;
  int stride = gridDim.x * blockDim.x;
  for (int e = blockIdx.x * blockDim.x + threadIdx.x; e < EE; e += stride) {
    int d = eidx(ei, (long long)EE + e, f64);
    atomicAdd(&cnt[d], 1);
  }
}

__global__ void k_dis(const int* __restrict__ cnt, float* dis) {
  int i = blockIdx.x * blockDim.x + threadIdx.x;
  if (i < NN) dis[i] = rsqrtf((float)(cnt[i] + 1));  // +1 self-loop, always > 0
}

// single-block exclusive scan of cnt -> rowptr (and pos = rowptr copy)
__global__ __launch_bounds__(SCAN_T) void k_scan(const int* __restrict__ cnt,
                                                 int* __restrict__ rowptr,
                                                 int* __restrict__ pos) {
  __shared__ int sums[SCAN_T];
  int tid = threadIdx.x;
  int base = tid * SCAN_CH;
  int vals[SCAN_CH];
  int local = 0;
#pragma unroll
  for (int j = 0; j < SCAN_CH; ++j) {
    int idx = base + j;
    int v = (idx < NN) ? cnt[idx] : 0;
    vals[j] = v;
    local += v;
  }
  sums[tid] = local;
  __syncthreads();
  for (int off = 1; off < SCAN_T; off <<= 1) {
    int v = (tid >= off) ? sums[tid - off] : 0;
    __syncthreads();
    sums[tid] += v;
    __syncthreads();
  }
  int run = sums[tid] - local;
#pragma unroll
  for (int j = 0; j < SCAN_CH; ++j) {
    int idx = base + j;
    if (idx < NN) { rowptr[idx] = run; pos[idx] = run; }
    run += vals[j];
  }
  if (tid == SCAN_T - 1) rowptr[NN] = run;
}

// counting-sort scatter: col[p] = src, w[p] = dis[src]*dis[dst], sorted by dst
__global__ void k_scatter(const void* ei, const int* __restrict__ flag,
                          const float* __restrict__ dis,
                          int* __restrict__ pos, int* __restrict__ col,
                          float* __restrict__ w) {
  int f64 = *flag;
  int stride = gridDim.x * blockDim.x;
  for (int e = blockIdx.x * blockDim.x + threadIdx.x; e < EE; e += stride) {
    int s = eidx(ei, e, f64);
    int d = eidx(ei, (long long)EE + e, f64);
    int p = atomicAdd(&pos[d], 1);
    col[p] = s;
    w[p] = dis[s] * dis[d];
  }
}

// ---- register-tiled GEMM 1: T(bf16)[N][128] = X(f32) @ W1(f32) ----
// block: 64 rows x 128 cols; thread (tx,ty): rows rb+ty*4..+3, cols {tx*4..+3, 64+tx*4..+3}
__global__ __launch_bounds__(256) void k_gemm1(const float* __restrict__ X,
                                               const float* __restrict__ W,
                                               ushort* __restrict__ T) {
  __shared__ float Ws[FF * FF];  // 64 KB
  for (int i = threadIdx.x; i < FF * FF; i += 256) Ws[i] = W[i];
  __syncthreads();
  int tx = threadIdx.x & 15, ty = threadIdx.x >> 4;
  int rb = blockIdx.x * 64 + ty * 4;
  const float* xr[4];
#pragma unroll
  for (int i = 0; i < 4; ++i) xr[i] = X + (size_t)min(rb + i, NN - 1) * FF;
  float4 acc0[4] = {}, acc1[4] = {};
#pragma unroll 2
  for (int kk = 0; kk < FF; kk += 4) {
    float4 a[4];
#pragma unroll
    for (int i = 0; i < 4; ++i) a[i] = *(const float4*)(xr[i] + kk);
#pragma unroll
    for (int k = 0; k < 4; ++k) {
      float4 b0 = *(const float4*)&Ws[(kk + k) * FF + tx * 4];
      float4 b1 = *(const float4*)&Ws[(kk + k) * FF + 64 + tx * 4];
#pragma unroll
      for (int i = 0; i < 4; ++i) {
        float av = ((const float*)&a[i])[k];
        acc0[i].x = fmaf(av, b0.x, acc0[i].x); acc0[i].y = fmaf(av, b0.y, acc0[i].y);
        acc0[i].z = fmaf(av, b0.z, acc0[i].z); acc0[i].w = fmaf(av, b0.w, acc0[i].w);
        acc1[i].x = fmaf(av, b1.x, acc1[i].x); acc1[i].y = fmaf(av, b1.y, acc1[i].y);
        acc1[i].z = fmaf(av, b1.z, acc1[i].z); acc1[i].w = fmaf(av, b1.w, acc1[i].w);
      }
    }
  }
#pragma unroll
  for (int i = 0; i < 4; ++i) {
    int r = rb + i;
    if (r < NN) {
      uint2 p0 = { pack2(acc0[i].x, acc0[i].y), pack2(acc0[i].z, acc0[i].w) };
      uint2 p1 = { pack2(acc1[i].x, acc1[i].y), pack2(acc1[i].z, acc1[i].w) };
      *(uint2*)(T + (size_t)r * FF + tx * 4) = p0;
      *(uint2*)(T + (size_t)r * FF + 64 + tx * 4) = p1;
    }
  }
}

// ---- register-tiled GEMM 2: out = A(bf16) @ [Wmu|Wlv] + [bmu|blv], split store ----
__global__ __launch_bounds__(256) void k_gemm2(const ushort* __restrict__ A,
                                               const float* __restrict__ Wmu,
                                               const float* __restrict__ bmu,
                                               const float* __restrict__ Wlv,
                                               const float* __restrict__ blv,
                                               float* __restrict__ out) {
  __shared__ float Ws[FF * FF];  // [k][c]: c<64 -> Wmu, c>=64 -> Wlv
  __shared__ float sb[FF];
  for (int i = threadIdx.x; i < FF * OO; i += 256) {
    int k = i >> 6, c = i & 63;
    Ws[k * FF + c] = Wmu[i];
    Ws[k * FF + 64 + c] = Wlv[i];
  }
  if (threadIdx.x < FF)
    sb[threadIdx.x] = (threadIdx.x < OO) ? bmu[threadIdx.x] : blv[threadIdx.x - OO];
  __syncthreads();
  int tx = threadIdx.x & 15, ty = threadIdx.x >> 4;
  int rb = blockIdx.x * 64 + ty * 4;
  const ushort* ar[4];
#pragma unroll
  for (int i = 0; i < 4; ++i) ar[i] = A + (size_t)min(rb + i, NN - 1) * FF;
  float4 acc0[4] = {}, acc1[4] = {};
#pragma unroll 2
  for (int kk = 0; kk < FF; kk += 4) {
    float af[4][4];
#pragma unroll
    for (int i = 0; i < 4; ++i) {
      uint2 v = *(const uint2*)(ar[i] + kk);
      af[i][0] = bflo(v.x); af[i][1] = bfhi(v.x);
      af[i][2] = bflo(v.y); af[i][3] = bfhi(v.y);
    }
#pragma unroll
    for (int k = 0; k < 4; ++k) {
      float4 b0 = *(const float4*)&Ws[(kk + k) * FF + tx * 4];
      float4 b1 = *(const float4*)&Ws[(kk + k) * FF + 64 + tx * 4];
#pragma unroll
      for (int i = 0; i < 4; ++i) {
        float av = af[i][k];
        acc0[i].x = fmaf(av, b0.x, acc0[i].x); acc0[i].y = fmaf(av, b0.y, acc0[i].y);
        acc0[i].z = fmaf(av, b0.z, acc0[i].z); acc0[i].w = fmaf(av, b0.w, acc0[i].w);
        acc1[i].x = fmaf(av, b1.x, acc1[i].x); acc1[i].y = fmaf(av, b1.y, acc1[i].y);
        acc1[i].z = fmaf(av, b1.z, acc1[i].z); acc1[i].w = fmaf(av, b1.w, acc1[i].w);
      }
    }
  }
  float4 bias0 = *(const float4*)&sb[tx * 4];
  float4 bias1 = *(const float4*)&sb[64 + tx * 4];
#pragma unroll
  for (int i = 0; i < 4; ++i) {
    int r = rb + i;
    if (r < NN) {
      float4 o0 = acc0[i], o1 = acc1[i];
      o0.x += bias0.x; o0.y += bias0.y; o0.z += bias0.z; o0.w += bias0.w;
      o1.x += bias1.x; o1.y += bias1.y; o1.z += bias1.z; o1.w += bias1.w;
      *(float4*)(out + (size_t)r * OO + tx * 4) = o0;                      // mu
      *(float4*)(out + (size_t)NN * OO + (size_t)r * OO + tx * 4) = o1;    // logvar
    }
  }
}

// one wave per node, bf16 features: acc = dis[i]^2*feat[i] + sum_e w[e]*feat[col[e]]
// LN=1: fused bias+ReLU+LayerNorm epilogue (conv1); LN=0: raw write (conv2)
template <int LN>
__global__ __launch_bounds__(256) void k_gather(const int* __restrict__ rowptr,
                                                const int* __restrict__ col,
                                                const float* __restrict__ w,
                                                const float* __restrict__ dis,
                                                const ushort* __restrict__ feat,
                                                const float* __restrict__ b1,
                                                const float* __restrict__ gamma,
                                                const float* __restrict__ beta,
                                                ushort* __restrict__ outp) {
  int node = blockIdx.x * 4 + (threadIdx.x >> 6);
  if (node >= NN) return;
  int lane = threadIdx.x & 63;
  float di = dis[node];
  float sw = di * di;
  uint sv = ((const uint*)(feat + ((size_t)node << 7)))[lane];
  float ax = sw * bflo(sv), ay = sw * bfhi(sv);
  int e = rowptr[node], end = rowptr[node + 1];
  for (; e + 3 < end; e += 4) {
    int s0 = col[e], s1 = col[e + 1], s2 = col[e + 2], s3 = col[e + 3];
    float w0 = w[e], w1 = w[e + 1], w2 = w[e + 2], w3 = w[e + 3];
    uint v0 = ((const uint*)(feat + ((size_t)s0 << 7)))[lane];
    uint v1 = ((const uint*)(feat + ((size_t)s1 << 7)))[lane];
    uint v2 = ((const uint*)(feat + ((size_t)s2 << 7)))[lane];
    uint v3 = ((const uint*)(feat + ((size_t)s3 << 7)))[lane];
    ax = fmaf(w0, bflo(v0), ax); ay = fmaf(w0, bfhi(v0), ay);
    ax = fmaf(w1, bflo(v1), ax); ay = fmaf(w1, bfhi(v1), ay);
    ax = fmaf(w2, bflo(v2), ax); ay = fmaf(w2, bfhi(v2), ay);
    ax = fmaf(w3, bflo(v3), ax); ay = fmaf(w3, bfhi(v3), ay);
  }
  for (; e < end; ++e) {
    int s0 = col[e];
    float w0 = w[e];
    uint v0 = ((const uint*)(feat + ((size_t)s0 << 7)))[lane];
    ax = fmaf(w0, bflo(v0), ax); ay = fmaf(w0, bfhi(v0), ay);
  }
  float ox, oy;
  if (LN) {
    float b0 = b1[2 * lane], b1v = b1[2 * lane + 1];
    float a0 = fmaxf(ax + b0, 0.f);
    float a1 = fmaxf(ay + b1v, 0.f);
    float s = a0 + a1, sq = a0 * a0 + a1 * a1;
#pragma unroll
    for (int m = 1; m < 64; m <<= 1) {
      s += __shfl_xor(s, m);
      sq += __shfl_xor(sq, m);
    }
    float mean = s * (1.f / 128.f);
    float var = sq * (1.f / 128.f) - mean * mean;
    float rstd = rsqrtf(var + EPSF);
    float g0 = gamma[2 * lane], g1 = gamma[2 * lane + 1];
    float be0 = beta[2 * lane], be1 = beta[2 * lane + 1];
    ox = (a0 - mean) * rstd * g0 + be0;
    oy = (a1 - mean) * rstd * g1 + be1;
  } else {
    ox = ax; oy = ay;
  }
  ((uint*)(outp + ((size_t)node << 7)))[lane] = pack2(ox, oy);
}

extern "C" void kernel_launch(void* const* d_in, const int* in_sizes, int n_in,
                              void* d_out, int out_size, void* d_ws, size_t ws_size,
                              hipStream_t stream) {
  const float* x     = (const float*)d_in[0];
  const void*  ei    = d_in[1];
  const float* W1    = (const float*)d_in[2];
  const float* b1    = (const float*)d_in[3];
  const float* gamma = (const float*)d_in[4];
  const float* beta  = (const float*)d_in[5];
  const float* Wmu   = (const float*)d_in[6];
  const float* bmu   = (const float*)d_in[7];
  const float* Wlv   = (const float*)d_in[8];
  const float* blv   = (const float*)d_in[9];
  float* out = (float*)d_out;

  // workspace (4B words): [flag 64][cnt N][rowptr N+16][pos N][dis N][col E][w E]
  //                       [align][t bf16 N*128][h bf16 N*128][t2 bf16 N*128]  ~46 MB
  int*   flag   = (int*)d_ws;
  int*   cnt    = flag + 64;
  int*   rowptr = cnt + NN;
  int*   pos    = rowptr + (NN + 16);
  float* dis    = (float*)(pos + NN);
  int*   col    = (int*)(dis + NN);
  float* w      = (float*)(col + EE);
  size_t off32  = (size_t)(64 + NN + (NN + 16) + NN + NN + EE + EE);
  off32 = (off32 + 63) & ~(size_t)63;  // 256B align for bf16 tables
  ushort* t  = (ushort*)((int*)d_ws + off32);
  ushort* h  = t + (size_t)NN * FF;
  ushort* t2 = h + (size_t)NN * FF;

  k_detect<<<1, 64, 0, stream>>>(ei, flag);
  k_cnt_init<<<(NN + 255) / 256, 256, 0, stream>>>(cnt);
  k_deg_edges<<<1024, 256, 0, stream>>>(ei, flag, cnt);
  k_dis<<<(NN + 255) / 256, 256, 0, stream>>>(cnt, dis);
  k_scan<<<1, SCAN_T, 0, stream>>>(cnt, rowptr, pos);
  k_scatter<<<1024, 256, 0, stream>>>(ei, flag, dis, pos, col, w);

  int gblk = (NN + 63) / 64;  // 782
  k_gemm1<<<gblk, 256, 0, stream>>>(x, W1, t);
  k_gather<1><<<(NN + 3) / 4, 256, 0, stream>>>(rowptr, col, w, dis, t, b1, gamma, beta, h);
  k_gather<0><<<(NN + 3) / 4, 256, 0, stream>>>(rowptr, col, w, dis, h, b1, gamma, beta, t2);
  k_gemm2<<<gblk, 256, 0, stream>>>(t2, Wmu, bmu, Wlv, blv, out);
}

// Round 4
// 238.457 us; speedup vs baseline: 6.6190x; 1.3095x over previous
//
#include <hip/hip_runtime.h>

#define NN 50000
#define EE 800000
#define FF 128
#define OO 64
#define EPSF 1e-5f
#define SCB 196  // ceil(NN / 256)

typedef unsigned int uint;
typedef unsigned short ushort;

// ---- bf16 helpers (RTNE pack, cheap unpack) ----
__device__ __forceinline__ float bflo(uint v) { return __uint_as_float(v << 16); }
__device__ __forceinline__ float bfhi(uint v) { return __uint_as_float(v & 0xFFFF0000u); }
__device__ __forceinline__ uint f2bf(float f) {
  uint b = __float_as_uint(f);
  return (b + 0x7FFFu + ((b >> 16) & 1u)) >> 16;
}
__device__ __forceinline__ uint pack2(float x, float y) { return f2bf(x) | (f2bf(y) << 16); }

// ---- edge-index access: handles both int32 and int64 serialized layouts ----
__device__ __forceinline__ int eidx(const void* ei, long long pos, int f64) {
  if (f64) return (int)((const long long*)ei)[pos];
  return ((const int*)ei)[pos];
}

__global__ void k_detect(const void* ei, int* flag) {
  if (threadIdx.x == 0 && blockIdx.x == 0) {
    const int* p = (const int*)ei;
    int any = 0;
    for (int i = 1; i < 128; i += 2) any |= p[i];  // high words all 0 <=> int64
    *flag = (any == 0) ? 1 : 0;
  }
}

__global__ void k_cnt_init(int* cnt) {
  int i = blockIdx.x * blockDim.x + threadIdx.x;
  if (i < NN) cnt[i] = 0;
}

__global__ void k_deg_edges(const void* ei, const int* __restrict__ flag, int* cnt) {
  int f64 = *flag;
  int stride = gridDim.x * blockDim.x;
  for (int e = blockIdx.x * blockDim.x + threadIdx.x; e < EE; e += stride) {
    int d = eidx(ei, (long long)EE + e, f64);
    atomicAdd(&cnt[d], 1);
  }
}

__global__ void k_dis(const int* __restrict__ cnt, float* dis) {
  int i = blockIdx.x * blockDim.x + threadIdx.x;
  if (i < NN) dis[i] = rsqrtf((float)(cnt[i] + 1));  // +1 self-loop, always > 0
}

// ---- 3-phase parallel exclusive scan of cnt[NN] -> rowptr/pos ----
__global__ __launch_bounds__(256) void k_scan_part(const int* __restrict__ cnt,
                                                   int* __restrict__ bsum) {
  int i = blockIdx.x * 256 + threadIdx.x;
  int v = (i < NN) ? cnt[i] : 0;
#pragma unroll
  for (int m = 1; m < 64; m <<= 1) v += __shfl_xor(v, m);
  __shared__ int ws[4];
  if ((threadIdx.x & 63) == 0) ws[threadIdx.x >> 6] = v;
  __syncthreads();
  if (threadIdx.x == 0) bsum[blockIdx.x] = ws[0] + ws[1] + ws[2] + ws[3];
}

__global__ __launch_bounds__(256) void k_scan_tops(const int* __restrict__ bsum,
                                                   int* __restrict__ boff,
                                                   int* __restrict__ rowptr) {
  __shared__ int s[256];
  int tid = threadIdx.x;
  int v = (tid < SCB) ? bsum[tid] : 0;
  s[tid] = v;
  __syncthreads();
  for (int off = 1; off < 256; off <<= 1) {
    int t = (tid >= off) ? s[tid - off] : 0;
    __syncthreads();
    s[tid] += t;
    __syncthreads();
  }
  if (tid < SCB) boff[tid] = s[tid] - v;  // exclusive
  if (tid == 255) rowptr[NN] = s[255];    // total = EE
}

__global__ __launch_bounds__(256) void k_scan_write(const int* __restrict__ cnt,
                                                    const int* __restrict__ boff,
                                                    int* __restrict__ rowptr,
                                                    int* __restrict__ pos) {
  int blk = blockIdx.x, tid = threadIdx.x;
  int i = blk * 256 + tid;
  int v = (i < NN) ? cnt[i] : 0;
  int lane = tid & 63, wid = tid >> 6;
  int inc = v;
#pragma unroll
  for (int off = 1; off < 64; off <<= 1) {
    int t = __shfl_up(inc, off);
    if (lane >= off) inc += t;
  }
  __shared__ int wsum[4];
  if (lane == 63) wsum[wid] = inc;
  __syncthreads();
  int wadd = 0;
  for (int wj = 0; wj < wid; ++wj) wadd += wsum[wj];
  int exc = inc - v + wadd + boff[blk];
  if (i < NN) { rowptr[i] = exc; pos[i] = exc; }
}

// counting-sort scatter: cw[p] = (src, dis[src]*dis[dst]) packed, sorted by dst
__global__ void k_scatter(const void* ei, const int* __restrict__ flag,
                          const float* __restrict__ dis,
                          int* __restrict__ pos, int2* __restrict__ cw) {
  int f64 = *flag;
  int stride = gridDim.x * blockDim.x;
  for (int e = blockIdx.x * blockDim.x + threadIdx.x; e < EE; e += stride) {
    int s = eidx(ei, e, f64);
    int d = eidx(ei, (long long)EE + e, f64);
    int p = atomicAdd(&pos[d], 1);
    int2 v;
    v.x = s;
    v.y = __float_as_int(dis[s] * dis[d]);
    cw[p] = v;
  }
}

// ---- register-tiled GEMM 1: T(bf16)[N][128] = X(f32) @ W1(f32) ----
__global__ __launch_bounds__(256) void k_gemm1(const float* __restrict__ X,
                                               const float* __restrict__ W,
                                               ushort* __restrict__ T) {
  __shared__ float Ws[FF * FF];  // 64 KB
  for (int i = threadIdx.x; i < FF * FF; i += 256) Ws[i] = W[i];
  __syncthreads();
  int tx = threadIdx.x & 15, ty = threadIdx.x >> 4;
  int rb = blockIdx.x * 64 + ty * 4;
  const float* xr[4];
#pragma unroll
  for (int i = 0; i < 4; ++i) xr[i] = X + (size_t)min(rb + i, NN - 1) * FF;
  float4 acc0[4] = {}, acc1[4] = {};
#pragma unroll 2
  for (int kk = 0; kk < FF; kk += 4) {
    float4 a[4];
#pragma unroll
    for (int i = 0; i < 4; ++i) a[i] = *(const float4*)(xr[i] + kk);
#pragma unroll
    for (int k = 0; k < 4; ++k) {
      float4 b0 = *(const float4*)&Ws[(kk + k) * FF + tx * 4];
      float4 b1 = *(const float4*)&Ws[(kk + k) * FF + 64 + tx * 4];
#pragma unroll
      for (int i = 0; i < 4; ++i) {
        float av = ((const float*)&a[i])[k];
        acc0[i].x = fmaf(av, b0.x, acc0[i].x); acc0[i].y = fmaf(av, b0.y, acc0[i].y);
        acc0[i].z = fmaf(av, b0.z, acc0[i].z); acc0[i].w = fmaf(av, b0.w, acc0[i].w);
        acc1[i].x = fmaf(av, b1.x, acc1[i].x); acc1[i].y = fmaf(av, b1.y, acc1[i].y);
        acc1[i].z = fmaf(av, b1.z, acc1[i].z); acc1[i].w = fmaf(av, b1.w, acc1[i].w);
      }
    }
  }
#pragma unroll
  for (int i = 0; i < 4; ++i) {
    int r = rb + i;
    if (r < NN) {
      uint2 p0 = { pack2(acc0[i].x, acc0[i].y), pack2(acc0[i].z, acc0[i].w) };
      uint2 p1 = { pack2(acc1[i].x, acc1[i].y), pack2(acc1[i].z, acc1[i].w) };
      *(uint2*)(T + (size_t)r * FF + tx * 4) = p0;
      *(uint2*)(T + (size_t)r * FF + 64 + tx * 4) = p1;
    }
  }
}

// ---- register-tiled GEMM 2: out = A(bf16) @ [Wmu|Wlv] + [bmu|blv], split store ----
__global__ __launch_bounds__(256) void k_gemm2(const ushort* __restrict__ A,
                                               const float* __restrict__ Wmu,
                                               const float* __restrict__ bmu,
                                               const float* __restrict__ Wlv,
                                               const float* __restrict__ blv,
                                               float* __restrict__ out) {
  __shared__ float Ws[FF * FF];  // [k][c]: c<64 -> Wmu, c>=64 -> Wlv
  __shared__ float sb[FF];
  for (int i = threadIdx.x; i < FF * OO; i += 256) {
    int k = i >> 6, c = i & 63;
    Ws[k * FF + c] = Wmu[i];
    Ws[k * FF + 64 + c] = Wlv[i];
  }
  if (threadIdx.x < FF)
    sb[threadIdx.x] = (threadIdx.x < OO) ? bmu[threadIdx.x] : blv[threadIdx.x - OO];
  __syncthreads();
  int tx = threadIdx.x & 15, ty = threadIdx.x >> 4;
  int rb = blockIdx.x * 64 + ty * 4;
  const ushort* ar[4];
#pragma unroll
  for (int i = 0; i < 4; ++i) ar[i] = A + (size_t)min(rb + i, NN - 1) * FF;
  float4 acc0[4] = {}, acc1[4] = {};
#pragma unroll 2
  for (int kk = 0; kk < FF; kk += 4) {
    float af[4][4];
#pragma unroll
    for (int i = 0; i < 4; ++i) {
      uint2 v = *(const uint2*)(ar[i] + kk);
      af[i][0] = bflo(v.x); af[i][1] = bfhi(v.x);
      af[i][2] = bflo(v.y); af[i][3] = bfhi(v.y);
    }
#pragma unroll
    for (int k = 0; k < 4; ++k) {
      float4 b0 = *(const float4*)&Ws[(kk + k) * FF + tx * 4];
      float4 b1 = *(const float4*)&Ws[(kk + k) * FF + 64 + tx * 4];
#pragma unroll
      for (int i = 0; i < 4; ++i) {
        float av = af[i][k];
        acc0[i].x = fmaf(av, b0.x, acc0[i].x); acc0[i].y = fmaf(av, b0.y, acc0[i].y);
        acc0[i].z = fmaf(av, b0.z, acc0[i].z); acc0[i].w = fmaf(av, b0.w, acc0[i].w);
        acc1[i].x = fmaf(av, b1.x, acc1[i].x); acc1[i].y = fmaf(av, b1.y, acc1[i].y);
        acc1[i].z = fmaf(av, b1.z, acc1[i].z); acc1[i].w = fmaf(av, b1.w, acc1[i].w);
      }
    }
  }
  float4 bias0 = *(const float4*)&sb[tx * 4];
  float4 bias1 = *(const float4*)&sb[64 + tx * 4];
#pragma unroll
  for (int i = 0; i < 4; ++i) {
    int r = rb + i;
    if (r < NN) {
      float4 o0 = acc0[i], o1 = acc1[i];
      o0.x += bias0.x; o0.y += bias0.y; o0.z += bias0.z; o0.w += bias0.w;
      o1.x += bias1.x; o1.y += bias1.y; o1.z += bias1.z; o1.w += bias1.w;
      *(float4*)(out + (size_t)r * OO + tx * 4) = o0;                      // mu
      *(float4*)(out + (size_t)NN * OO + (size_t)r * OO + tx * 4) = o1;    // logvar
    }
  }
}

// one wave per node, bf16 features: acc = dis[i]^2*feat[i] + sum_e w[e]*feat[col[e]]
// LN=1: fused bias+ReLU+LayerNorm epilogue (conv1); LN=0: raw write (conv2)
template <int LN>
__global__ __launch_bounds__(256) void k_gather(const int* __restrict__ rowptr,
                                                const int2* __restrict__ cw,
                                                const float* __restrict__ dis,
                                                const ushort* __restrict__ feat,
                                                const float* __restrict__ b1,
                                                const float* __restrict__ gamma,
                                                const float* __restrict__ beta,
                                                ushort* __restrict__ outp) {
  int node = blockIdx.x * 4 + (threadIdx.x >> 6);
  if (node >= NN) return;
  int lane = threadIdx.x & 63;
  float di = dis[node];
  float sw = di * di;
  uint sv = ((const uint*)(feat + ((size_t)node << 7)))[lane];
  float ax = sw * bflo(sv), ay = sw * bfhi(sv);
  int e = rowptr[node], end = rowptr[node + 1];
  for (; e + 3 < end; e += 4) {
    int2 c0 = cw[e], c1 = cw[e + 1], c2 = cw[e + 2], c3 = cw[e + 3];
    uint v0 = ((const uint*)(feat + ((size_t)c0.x << 7)))[lane];
    uint v1 = ((const uint*)(feat + ((size_t)c1.x << 7)))[lane];
    uint v2 = ((const uint*)(feat + ((size_t)c2.x << 7)))[lane];
    uint v3 = ((const uint*)(feat + ((size_t)c3.x << 7)))[lane];
    float w0 = __int_as_float(c0.y), w1 = __int_as_float(c1.y);
    float w2 = __int_as_float(c2.y), w3 = __int_as_float(c3.y);
    ax = fmaf(w0, bflo(v0), ax); ay = fmaf(w0, bfhi(v0), ay);
    ax = fmaf(w1, bflo(v1), ax); ay = fmaf(w1, bfhi(v1), ay);
    ax = fmaf(w2, bflo(v2), ax); ay = fmaf(w2, bfhi(v2), ay);
    ax = fmaf(w3, bflo(v3), ax); ay = fmaf(w3, bfhi(v3), ay);
  }
  for (; e < end; ++e) {
    int2 c0 = cw[e];
    uint v0 = ((const uint*)(feat + ((size_t)c0.x << 7)))[lane];
    float w0 = __int_as_float(c0.y);
    ax = fmaf(w0, bflo(v0), ax); ay = fmaf(w0, bfhi(v0), ay);
  }
  float ox, oy;
  if (LN) {
    float b0 = b1[2 * lane], b1v = b1[2 * lane + 1];
    float a0 = fmaxf(ax + b0, 0.f);
    float a1 = fmaxf(ay + b1v, 0.f);
    float s = a0 + a1, sq = a0 * a0 + a1 * a1;
#pragma unroll
    for (int m = 1; m < 64; m <<= 1) {
      s += __shfl_xor(s, m);
      sq += __shfl_xor(sq, m);
    }
    float mean = s * (1.f / 128.f);
    float var = sq * (1.f / 128.f) - mean * mean;
    float rstd = rsqrtf(var + EPSF);
    float g0 = gamma[2 * lane], g1 = gamma[2 * lane + 1];
    float be0 = beta[2 * lane], be1 = beta[2 * lane + 1];
    ox = (a0 - mean) * rstd * g0 + be0;
    oy = (a1 - mean) * rstd * g1 + be1;
  } else {
    ox = ax; oy = ay;
  }
  ((uint*)(outp + ((size_t)node << 7)))[lane] = pack2(ox, oy);
}

extern "C" void kernel_launch(void* const* d_in, const int* in_sizes, int n_in,
                              void* d_out, int out_size, void* d_ws, size_t ws_size,
                              hipStream_t stream) {
  const float* x     = (const float*)d_in[0];
  const void*  ei    = d_in[1];
  const float* W1    = (const float*)d_in[2];
  const float* b1    = (const float*)d_in[3];
  const float* gamma = (const float*)d_in[4];
  const float* beta  = (const float*)d_in[5];
  const float* Wmu   = (const float*)d_in[6];
  const float* bmu   = (const float*)d_in[7];
  const float* Wlv   = (const float*)d_in[8];
  const float* blv   = (const float*)d_in[9];
  float* out = (float*)d_out;

  // workspace (4B words):
  // [flag 64][cnt N][rowptr N+16][pos N][dis N][bsum 256][boff 256]
  // [align 64][cw int2 E][t bf16 N*128][h bf16 N*128][t2 bf16 N*128]   ~45.6 MB
  int*   flag   = (int*)d_ws;
  int*   cnt    = flag + 64;
  int*   rowptr = cnt + NN;
  int*   pos    = rowptr + (NN + 16);
  float* dis    = (float*)(pos + NN);
  int*   bsum   = (int*)(dis + NN);
  int*   boff   = bsum + 256;
  size_t off32  = (size_t)(64 + NN + (NN + 16) + NN + NN + 256 + 256);
  off32 = (off32 + 63) & ~(size_t)63;
  int2*  cw     = (int2*)((int*)d_ws + off32);
  ushort* t  = (ushort*)(cw + EE);
  ushort* h  = t + (size_t)NN * FF;
  ushort* t2 = h + (size_t)NN * FF;

  k_detect<<<1, 64, 0, stream>>>(ei, flag);
  k_cnt_init<<<(NN + 255) / 256, 256, 0, stream>>>(cnt);
  k_deg_edges<<<1024, 256, 0, stream>>>(ei, flag, cnt);
  k_dis<<<(NN + 255) / 256, 256, 0, stream>>>(cnt, dis);
  k_scan_part<<<SCB, 256, 0, stream>>>(cnt, bsum);
  k_scan_tops<<<1, 256, 0, stream>>>(bsum, boff, rowptr);
  k_scan_write<<<SCB, 256, 0, stream>>>(cnt, boff, rowptr, pos);
  k_scatter<<<1024, 256, 0, stream>>>(ei, flag, dis, pos, cw);

  int gblk = (NN + 63) / 64;  // 782
  k_gemm1<<<gblk, 256, 0, stream>>>(x, W1, t);
  k_gather<1><<<(NN + 3) / 4, 256, 0, stream>>>(rowptr, cw, dis, t, b1, gamma, beta, h);
  k_gather<0><<<(NN + 3) / 4, 256, 0, stream>>>(rowptr, cw, dis, h, b1, gamma, beta, t2);
  k_gemm2<<<gblk, 256, 0, stream>>>(t2, Wmu, bmu, Wlv, blv, out);
}

// Round 5
// 203.807 us; speedup vs baseline: 7.7443x; 1.1700x over previous
//
#include <hip/hip_runtime.h>

#define NN 50000
#define EE 800000
#define FF 128
#define OO 64
#define EPSF 1e-5f
#define SCB 196  // ceil(NN / 256)
#define EBLK 3125  // EE / 256

typedef unsigned int uint;
typedef unsigned short ushort;

// ---- bf16 helpers (RTNE pack, cheap unpack) ----
__device__ __forceinline__ float bflo(uint v) { return __uint_as_float(v << 16); }
__device__ __forceinline__ float bfhi(uint v) { return __uint_as_float(v & 0xFFFF0000u); }
__device__ __forceinline__ uint f2bf(float f) {
  uint b = __float_as_uint(f);
  return (b + 0x7FFFu + ((b >> 16) & 1u)) >> 16;
}
__device__ __forceinline__ uint pack2(float x, float y) { return f2bf(x) | (f2bf(y) << 16); }

// ---- edge-index access: handles both int32 and int64 serialized layouts ----
__device__ __forceinline__ int eidx(const void* ei, long long pos, int f64) {
  if (f64) return (int)((const long long*)ei)[pos];
  return ((const int*)ei)[pos];
}

__global__ void k_detect(const void* ei, int* flag) {
  if (threadIdx.x == 0 && blockIdx.x == 0) {
    const int* p = (const int*)ei;
    int any = 0;
    for (int i = 1; i < 128; i += 2) any |= p[i];  // high words all 0 <=> int64
    *flag = (any == 0) ? 1 : 0;
  }
}

__global__ void k_cnt_init(int* cnt) {
  int i = blockIdx.x * blockDim.x + threadIdx.x;
  if (i < NN) cnt[i] = 0;
}

// one thread per edge: count degree AND record this edge's rank within its dst row
__global__ void k_deg_rank(const void* ei, const int* __restrict__ flag,
                           int* __restrict__ cnt, int* __restrict__ rank) {
  int e = blockIdx.x * 256 + threadIdx.x;
  if (e >= EE) return;
  int f64 = *flag;
  int d = eidx(ei, (long long)EE + e, f64);
  rank[e] = atomicAdd(&cnt[d], 1);
}

__global__ void k_dis(const int* __restrict__ cnt, float* dis) {
  int i = blockIdx.x * blockDim.x + threadIdx.x;
  if (i < NN) dis[i] = rsqrtf((float)(cnt[i] + 1));  // +1 self-loop, always > 0
}

// ---- 3-phase parallel exclusive scan of cnt[NN] -> rowptr ----
__global__ __launch_bounds__(256) void k_scan_part(const int* __restrict__ cnt,
                                                   int* __restrict__ bsum) {
  int i = blockIdx.x * 256 + threadIdx.x;
  int v = (i < NN) ? cnt[i] : 0;
#pragma unroll
  for (int m = 1; m < 64; m <<= 1) v += __shfl_xor(v, m);
  __shared__ int ws[4];
  if ((threadIdx.x & 63) == 0) ws[threadIdx.x >> 6] = v;
  __syncthreads();
  if (threadIdx.x == 0) bsum[blockIdx.x] = ws[0] + ws[1] + ws[2] + ws[3];
}

__global__ __launch_bounds__(256) void k_scan_tops(const int* __restrict__ bsum,
                                                   int* __restrict__ boff,
                                                   int* __restrict__ rowptr) {
  __shared__ int s[256];
  int tid = threadIdx.x;
  int v = (tid < SCB) ? bsum[tid] : 0;
  s[tid] = v;
  __syncthreads();
  for (int off = 1; off < 256; off <<= 1) {
    int t = (tid >= off) ? s[tid - off] : 0;
    __syncthreads();
    s[tid] += t;
    __syncthreads();
  }
  if (tid < SCB) boff[tid] = s[tid] - v;  // exclusive
  if (tid == 255) rowptr[NN] = s[255];    // total = EE
}

__global__ __launch_bounds__(256) void k_scan_write(const int* __restrict__ cnt,
                                                    const int* __restrict__ boff,
                                                    int* __restrict__ rowptr) {
  int blk = blockIdx.x, tid = threadIdx.x;
  int i = blk * 256 + tid;
  int v = (i < NN) ? cnt[i] : 0;
  int lane = tid & 63, wid = tid >> 6;
  int inc = v;
#pragma unroll
  for (int off = 1; off < 64; off <<= 1) {
    int t = __shfl_up(inc, off);
    if (lane >= off) inc += t;
  }
  __shared__ int wsum[4];
  if (lane == 63) wsum[wid] = inc;
  __syncthreads();
  int wadd = 0;
  for (int wj = 0; wj < wid; ++wj) wadd += wsum[wj];
  int exc = inc - v + wadd + boff[blk];
  if (i < NN) rowptr[i] = exc;
}

// atomic-free scatter: cw[rowptr[d]+rank[e]] = (src, dis[src]*dis[dst])
__global__ void k_scatter(const void* ei, const int* __restrict__ flag,
                          const float* __restrict__ dis,
                          const int* __restrict__ rowptr,
                          const int* __restrict__ rank,
                          int2* __restrict__ cw) {
  int e = blockIdx.x * 256 + threadIdx.x;
  if (e >= EE) return;
  int f64 = *flag;
  int s = eidx(ei, e, f64);
  int d = eidx(ei, (long long)EE + e, f64);
  int p = rowptr[d] + rank[e];
  int2 v;
  v.x = s;
  v.y = __float_as_int(dis[s] * dis[d]);
  cw[p] = v;
}

// ---- register-tiled GEMM 1: T(bf16)[N][128] = X(f32) @ W1(f32) ----
__global__ __launch_bounds__(256) void k_gemm1(const float* __restrict__ X,
                                               const float* __restrict__ W,
                                               ushort* __restrict__ T) {
  __shared__ float Ws[FF * FF];  // 64 KB
  for (int i = threadIdx.x; i < FF * FF; i += 256) Ws[i] = W[i];
  __syncthreads();
  int tx = threadIdx.x & 15, ty = threadIdx.x >> 4;
  int rb = blockIdx.x * 64 + ty * 4;
  const float* xr[4];
#pragma unroll
  for (int i = 0; i < 4; ++i) xr[i] = X + (size_t)min(rb + i, NN - 1) * FF;
  float4 acc0[4] = {}, acc1[4] = {};
#pragma unroll 2
  for (int kk = 0; kk < FF; kk += 4) {
    float4 a[4];
#pragma unroll
    for (int i = 0; i < 4; ++i) a[i] = *(const float4*)(xr[i] + kk);
#pragma unroll
    for (int k = 0; k < 4; ++k) {
      float4 b0 = *(const float4*)&Ws[(kk + k) * FF + tx * 4];
      float4 b1 = *(const float4*)&Ws[(kk + k) * FF + 64 + tx * 4];
#pragma unroll
      for (int i = 0; i < 4; ++i) {
        float av = ((const float*)&a[i])[k];
        acc0[i].x = fmaf(av, b0.x, acc0[i].x); acc0[i].y = fmaf(av, b0.y, acc0[i].y);
        acc0[i].z = fmaf(av, b0.z, acc0[i].z); acc0[i].w = fmaf(av, b0.w, acc0[i].w);
        acc1[i].x = fmaf(av, b1.x, acc1[i].x); acc1[i].y = fmaf(av, b1.y, acc1[i].y);
        acc1[i].z = fmaf(av, b1.z, acc1[i].z); acc1[i].w = fmaf(av, b1.w, acc1[i].w);
      }
    }
  }
#pragma unroll
  for (int i = 0; i < 4; ++i) {
    int r = rb + i;
    if (r < NN) {
      uint2 p0 = { pack2(acc0[i].x, acc0[i].y), pack2(acc0[i].z, acc0[i].w) };
      uint2 p1 = { pack2(acc1[i].x, acc1[i].y), pack2(acc1[i].z, acc1[i].w) };
      *(uint2*)(T + (size_t)r * FF + tx * 4) = p0;
      *(uint2*)(T + (size_t)r * FF + 64 + tx * 4) = p1;
    }
  }
}

// ---- register-tiled GEMM 2: out = A(bf16) @ [Wmu|Wlv] + [bmu|blv], split store ----
__global__ __launch_bounds__(256) void k_gemm2(const ushort* __restrict__ A,
                                               const float* __restrict__ Wmu,
                                               const float* __restrict__ bmu,
                                               const float* __restrict__ Wlv,
                                               const float* __restrict__ blv,
                                               float* __restrict__ out) {
  __shared__ float Ws[FF * FF];  // [k][c]: c<64 -> Wmu, c>=64 -> Wlv
  __shared__ float sb[FF];
  for (int i = threadIdx.x; i < FF * OO; i += 256) {
    int k = i >> 6, c = i & 63;
    Ws[k * FF + c] = Wmu[i];
    Ws[k * FF + 64 + c] = Wlv[i];
  }
  if (threadIdx.x < FF)
    sb[threadIdx.x] = (threadIdx.x < OO) ? bmu[threadIdx.x] : blv[threadIdx.x - OO];
  __syncthreads();
  int tx = threadIdx.x & 15, ty = threadIdx.x >> 4;
  int rb = blockIdx.x * 64 + ty * 4;
  const ushort* ar[4];
#pragma unroll
  for (int i = 0; i < 4; ++i) ar[i] = A + (size_t)min(rb + i, NN - 1) * FF;
  float4 acc0[4] = {}, acc1[4] = {};
#pragma unroll 2
  for (int kk = 0; kk < FF; kk += 4) {
    float af[4][4];
#pragma unroll
    for (int i = 0; i < 4; ++i) {
      uint2 v = *(const uint2*)(ar[i] + kk);
      af[i][0] = bflo(v.x); af[i][1] = bfhi(v.x);
      af[i][2] = bflo(v.y); af[i][3] = bfhi(v.y);
    }
#pragma unroll
    for (int k = 0; k < 4; ++k) {
      float4 b0 = *(const float4*)&Ws[(kk + k) * FF + tx * 4];
      float4 b1 = *(const float4*)&Ws[(kk + k) * FF + 64 + tx * 4];
#pragma unroll
      for (int i = 0; i < 4; ++i) {
        float av = af[i][k];
        acc0[i].x = fmaf(av, b0.x, acc0[i].x); acc0[i].y = fmaf(av, b0.y, acc0[i].y);
        acc0[i].z = fmaf(av, b0.z, acc0[i].z); acc0[i].w = fmaf(av, b0.w, acc0[i].w);
        acc1[i].x = fmaf(av, b1.x, acc1[i].x); acc1[i].y = fmaf(av, b1.y, acc1[i].y);
        acc1[i].z = fmaf(av, b1.z, acc1[i].z); acc1[i].w = fmaf(av, b1.w, acc1[i].w);
      }
    }
  }
  float4 bias0 = *(const float4*)&sb[tx * 4];
  float4 bias1 = *(const float4*)&sb[64 + tx * 4];
#pragma unroll
  for (int i = 0; i < 4; ++i) {
    int r = rb + i;
    if (r < NN) {
      float4 o0 = acc0[i], o1 = acc1[i];
      o0.x += bias0.x; o0.y += bias0.y; o0.z += bias0.z; o0.w += bias0.w;
      o1.x += bias1.x; o1.y += bias1.y; o1.z += bias1.z; o1.w += bias1.w;
      *(float4*)(out + (size_t)r * OO + tx * 4) = o0;                      // mu
      *(float4*)(out + (size_t)NN * OO + (size_t)r * OO + tx * 4) = o1;    // logvar
    }
  }
}

// one wave per node, bf16 features, 8 outstanding row-loads per iter
// LN=1: fused bias+ReLU+LayerNorm epilogue (conv1); LN=0: raw write (conv2)
template <int LN>
__global__ __launch_bounds__(256) void k_gather(const int* __restrict__ rowptr,
                                                const int2* __restrict__ cw,
                                                const float* __restrict__ dis,
                                                const ushort* __restrict__ feat,
                                                const float* __restrict__ b1,
                                                const float* __restrict__ gamma,
                                                const float* __restrict__ beta,
                                                ushort* __restrict__ outp) {
  int node = blockIdx.x * 4 + (threadIdx.x >> 6);
  if (node >= NN) return;
  int lane = threadIdx.x & 63;
  float di = dis[node];
  float sw = di * di;
  uint sv = ((const uint*)(feat + ((size_t)node << 7)))[lane];
  float ax = sw * bflo(sv), ay = sw * bfhi(sv);
  int e = rowptr[node], end = rowptr[node + 1];
  for (; e + 7 < end; e += 8) {
    int2 c[8];
    uint v[8];
#pragma unroll
    for (int j = 0; j < 8; ++j) c[j] = cw[e + j];
#pragma unroll
    for (int j = 0; j < 8; ++j) v[j] = ((const uint*)(feat + ((size_t)c[j].x << 7)))[lane];
#pragma unroll
    for (int j = 0; j < 8; ++j) {
      float wj = __int_as_float(c[j].y);
      ax = fmaf(wj, bflo(v[j]), ax); ay = fmaf(wj, bfhi(v[j]), ay);
    }
  }
  if (e + 3 < end) {
    int2 c[4];
    uint v[4];
#pragma unroll
    for (int j = 0; j < 4; ++j) c[j] = cw[e + j];
#pragma unroll
    for (int j = 0; j < 4; ++j) v[j] = ((const uint*)(feat + ((size_t)c[j].x << 7)))[lane];
#pragma unroll
    for (int j = 0; j < 4; ++j) {
      float wj = __int_as_float(c[j].y);
      ax = fmaf(wj, bflo(v[j]), ax); ay = fmaf(wj, bfhi(v[j]), ay);
    }
    e += 4;
  }
  for (; e < end; ++e) {
    int2 c0 = cw[e];
    uint v0 = ((const uint*)(feat + ((size_t)c0.x << 7)))[lane];
    float w0 = __int_as_float(c0.y);
    ax = fmaf(w0, bflo(v0), ax); ay = fmaf(w0, bfhi(v0), ay);
  }
  float ox, oy;
  if (LN) {
    float b0 = b1[2 * lane], b1v = b1[2 * lane + 1];
    float a0 = fmaxf(ax + b0, 0.f);
    float a1 = fmaxf(ay + b1v, 0.f);
    float s = a0 + a1, sq = a0 * a0 + a1 * a1;
#pragma unroll
    for (int m = 1; m < 64; m <<= 1) {
      s += __shfl_xor(s, m);
      sq += __shfl_xor(sq, m);
    }
    float mean = s * (1.f / 128.f);
    float var = sq * (1.f / 128.f) - mean * mean;
    float rstd = rsqrtf(var + EPSF);
    float g0 = gamma[2 * lane], g1 = gamma[2 * lane + 1];
    float be0 = beta[2 * lane], be1 = beta[2 * lane + 1];
    ox = (a0 - mean) * rstd * g0 + be0;
    oy = (a1 - mean) * rstd * g1 + be1;
  } else {
    ox = ax; oy = ay;
  }
  ((uint*)(outp + ((size_t)node << 7)))[lane] = pack2(ox, oy);
}

extern "C" void kernel_launch(void* const* d_in, const int* in_sizes, int n_in,
                              void* d_out, int out_size, void* d_ws, size_t ws_size,
                              hipStream_t stream) {
  const float* x     = (const float*)d_in[0];
  const void*  ei    = d_in[1];
  const float* W1    = (const float*)d_in[2];
  const float* b1    = (const float*)d_in[3];
  const float* gamma = (const float*)d_in[4];
  const float* beta  = (const float*)d_in[5];
  const float* Wmu   = (const float*)d_in[6];
  const float* bmu   = (const float*)d_in[7];
  const float* Wlv   = (const float*)d_in[8];
  const float* blv   = (const float*)d_in[9];
  float* out = (float*)d_out;

  // workspace (4B words):
  // [flag 64][cnt N][rowptr N+16][dis N][bsum 256][boff 256][rank E]
  // [cw int2 E][t bf16 N*128][h bf16 N*128][t2 bf16 N*128]   ~48.6 MB
  int*   flag   = (int*)d_ws;
  int*   cnt    = flag + 64;
  int*   rowptr = cnt + NN;
  float* dis    = (float*)(rowptr + (NN + 16));
  int*   bsum   = (int*)(dis + NN);
  int*   boff   = bsum + 256;
  int*   rank   = boff + 256;
  size_t off32  = (size_t)(64 + NN + (NN + 16) + NN + 256 + 256 + EE);
  off32 = (off32 + 63) & ~(size_t)63;
  int2*  cw     = (int2*)((int*)d_ws + off32);
  ushort* t  = (ushort*)(cw + EE);
  ushort* h  = t + (size_t)NN * FF;
  ushort* t2 = h + (size_t)NN * FF;

  k_detect<<<1, 64, 0, stream>>>(ei, flag);
  k_cnt_init<<<(NN + 255) / 256, 256, 0, stream>>>(cnt);
  k_deg_rank<<<EBLK, 256, 0, stream>>>(ei, flag, cnt, rank);
  k_dis<<<(NN + 255) / 256, 256, 0, stream>>>(cnt, dis);
  k_scan_part<<<SCB, 256, 0, stream>>>(cnt, bsum);
  k_scan_tops<<<1, 256, 0, stream>>>(bsum, boff, rowptr);
  k_scan_write<<<SCB, 256, 0, stream>>>(cnt, boff, rowptr);
  k_scatter<<<EBLK, 256, 0, stream>>>(ei, flag, dis, rowptr, rank, cw);

  int gblk = (NN + 63) / 64;  // 782
  k_gemm1<<<gblk, 256, 0, stream>>>(x, W1, t);
  k_gather<1><<<(NN + 3) / 4, 256, 0, stream>>>(rowptr, cw, dis, t, b1, gamma, beta, h);
  k_gather<0><<<(NN + 3) / 4, 256, 0, stream>>>(rowptr, cw, dis, h, b1, gamma, beta, t2);
  k_gemm2<<<gblk, 256, 0, stream>>>(t2, Wmu, bmu, Wlv, blv, out);
}

// Round 6
// 168.863 us; speedup vs baseline: 9.3469x; 1.2069x over previous
//
#include <hip/hip_runtime.h>

#define NN 50000
#define EE 800000
#define FF 128
#define OO 64
#define EPSF 1e-5f
#define SCB 196    // ceil(NN / 256)
#define EBLK 3125  // EE / 256
#define GBLK 391   // ceil(NN / 128)

typedef unsigned int uint;
typedef unsigned short ushort;
typedef __attribute__((ext_vector_type(8))) short short8;  // 8 bf16 = 4 VGPR
typedef __attribute__((ext_vector_type(4))) float f32x4;

// ---- bf16 helpers (RTNE pack, cheap unpack) ----
__device__ __forceinline__ float bflo(uint v) { return __uint_as_float(v << 16); }
__device__ __forceinline__ float bfhi(uint v) { return __uint_as_float(v & 0xFFFF0000u); }
__device__ __forceinline__ uint f2bf(float f) {
  uint b = __float_as_uint(f);
  return (b + 0x7FFFu + ((b >> 16) & 1u)) >> 16;
}
__device__ __forceinline__ uint pack2(float x, float y) { return f2bf(x) | (f2bf(y) << 16); }

// ---- edge-index access: handles both int32 and int64 serialized layouts ----
__device__ __forceinline__ int eidx(const void* ei, long long pos, int f64) {
  if (f64) return (int)((const long long*)ei)[pos];
  return ((const int*)ei)[pos];
}

__global__ void k_detect(const void* ei, int* flag) {
  if (threadIdx.x == 0 && blockIdx.x == 0) {
    const int* p = (const int*)ei;
    int any = 0;
    for (int i = 1; i < 128; i += 2) any |= p[i];  // high words all 0 <=> int64
    *flag = (any == 0) ? 1 : 0;
  }
}

__global__ void k_cnt_init(int* cnt) {
  int i = blockIdx.x * blockDim.x + threadIdx.x;
  if (i < NN) cnt[i] = 0;
}

// one thread per edge: count degree AND record this edge's rank within its dst row
__global__ void k_deg_rank(const void* ei, const int* __restrict__ flag,
                           int* __restrict__ cnt, int* __restrict__ rank) {
  int e = blockIdx.x * 256 + threadIdx.x;
  if (e >= EE) return;
  int f64 = *flag;
  int d = eidx(ei, (long long)EE + e, f64);
  rank[e] = atomicAdd(&cnt[d], 1);
}

__global__ void k_dis(const int* __restrict__ cnt, float* dis) {
  int i = blockIdx.x * blockDim.x + threadIdx.x;
  if (i < NN) dis[i] = rsqrtf((float)(cnt[i] + 1));  // +1 self-loop, always > 0
}

// ---- 3-phase parallel exclusive scan of cnt[NN] -> rowptr ----
__global__ __launch_bounds__(256) void k_scan_part(const int* __restrict__ cnt,
                                                   int* __restrict__ bsum) {
  int i = blockIdx.x * 256 + threadIdx.x;
  int v = (i < NN) ? cnt[i] : 0;
#pragma unroll
  for (int m = 1; m < 64; m <<= 1) v += __shfl_xor(v, m);
  __shared__ int ws[4];
  if ((threadIdx.x & 63) == 0) ws[threadIdx.x >> 6] = v;
  __syncthreads();
  if (threadIdx.x == 0) bsum[blockIdx.x] = ws[0] + ws[1] + ws[2] + ws[3];
}

__global__ __launch_bounds__(256) void k_scan_tops(const int* __restrict__ bsum,
                                                   int* __restrict__ boff,
                                                   int* __restrict__ rowptr) {
  __shared__ int s[256];
  int tid = threadIdx.x;
  int v = (tid < SCB) ? bsum[tid] : 0;
  s[tid] = v;
  __syncthreads();
  for (int off = 1; off < 256; off <<= 1) {
    int t = (tid >= off) ? s[tid - off] : 0;
    __syncthreads();
    s[tid] += t;
    __syncthreads();
  }
  if (tid < SCB) boff[tid] = s[tid] - v;  // exclusive
  if (tid == 255) rowptr[NN] = s[255];    // total = EE
}

__global__ __launch_bounds__(256) void k_scan_write(const int* __restrict__ cnt,
                                                    const int* __restrict__ boff,
                                                    int* __restrict__ rowptr) {
  int blk = blockIdx.x, tid = threadIdx.x;
  int i = blk * 256 + tid;
  int v = (i < NN) ? cnt[i] : 0;
  int lane = tid & 63, wid = tid >> 6;
  int inc = v;
#pragma unroll
  for (int off = 1; off < 64; off <<= 1) {
    int t = __shfl_up(inc, off);
    if (lane >= off) inc += t;
  }
  __shared__ int wsum[4];
  if (lane == 63) wsum[wid] = inc;
  __syncthreads();
  int wadd = 0;
  for (int wj = 0; wj < wid; ++wj) wadd += wsum[wj];
  int exc = inc - v + wadd + boff[blk];
  if (i < NN) rowptr[i] = exc;
}

// atomic-free scatter: cw[rowptr[d]+rank[e]] = (src, dis[src]*dis[dst])
__global__ void k_scatter(const void* ei, const int* __restrict__ flag,
                          const float* __restrict__ dis,
                          const int* __restrict__ rowptr,
                          const int* __restrict__ rank,
                          int2* __restrict__ cw) {
  int e = blockIdx.x * 256 + threadIdx.x;
  if (e >= EE) return;
  int f64 = *flag;
  int s = eidx(ei, e, f64);
  int d = eidx(ei, (long long)EE + e, f64);
  int p = rowptr[d] + rank[e];
  int2 v;
  v.x = s;
  v.y = __float_as_int(dis[s] * dis[d]);
  cw[p] = v;
}

// swizzled LDS index for Wt[c][k] (ushort units): c*128 + (k ^ ((c&7)<<3))
__device__ __forceinline__ int wt_idx(int c, int k) {
  return c * 128 + (k ^ ((c & 7) << 3));
}

// ---- MFMA GEMM 1: T(bf16)[N][128] = X(f32) @ W1(f32->bf16) ----
// block: 128 rows, 4 waves; wave w: rows [blk*128 + w*32, +32), all 128 cols
__global__ __launch_bounds__(256) void k_gemm1(const float* __restrict__ X,
                                               const float* __restrict__ W,
                                               ushort* __restrict__ T) {
  __shared__ ushort Wt[FF * FF];  // 32 KB, Wt[c][k] swizzled
  for (int i = threadIdx.x; i < FF * FF; i += 256) {
    int k = i >> 7, c = i & 127;
    Wt[wt_idx(c, k)] = (ushort)f2bf(W[i]);
  }
  __syncthreads();
  int l = threadIdx.x & 63, wv = threadIdx.x >> 6;
  int rbase = blockIdx.x * 128 + wv * 32;
  int lr = l & 15, lk = (l >> 4) << 3;  // frag row/col within tile, k-offset
  f32x4 acc[2][8] = {};
#pragma unroll
  for (int kb = 0; kb < 4; ++kb) {
    int kk = kb * 32 + lk;
    short8 a[2];
#pragma unroll
    for (int rt = 0; rt < 2; ++rt) {
      int row = min(rbase + rt * 16 + lr, NN - 1);
      const float4* ap = (const float4*)(X + (size_t)row * FF + kk);
      float4 x0 = ap[0], x1 = ap[1];
      a[rt][0] = (short)f2bf(x0.x); a[rt][1] = (short)f2bf(x0.y);
      a[rt][2] = (short)f2bf(x0.z); a[rt][3] = (short)f2bf(x0.w);
      a[rt][4] = (short)f2bf(x1.x); a[rt][5] = (short)f2bf(x1.y);
      a[rt][6] = (short)f2bf(x1.z); a[rt][7] = (short)f2bf(x1.w);
    }
#pragma unroll
    for (int ct = 0; ct < 8; ++ct) {
      int c = ct * 16 + lr;
      short8 b = *(const short8*)&Wt[wt_idx(c, kk)];
      acc[0][ct] = __builtin_amdgcn_mfma_f32_16x16x32_bf16(a[0], b, acc[0][ct], 0, 0, 0);
      acc[1][ct] = __builtin_amdgcn_mfma_f32_16x16x32_bf16(a[1], b, acc[1][ct], 0, 0, 0);
    }
  }
  int rl = (l >> 4) * 4;  // C/D: col = lane&15, row = (lane>>4)*4 + reg
#pragma unroll
  for (int rt = 0; rt < 2; ++rt)
#pragma unroll
    for (int reg = 0; reg < 4; ++reg) {
      int row = rbase + rt * 16 + rl + reg;
      if (row < NN) {
#pragma unroll
        for (int ct = 0; ct < 8; ++ct)
          T[(size_t)row * FF + ct * 16 + lr] = (ushort)f2bf(acc[rt][ct][reg]);
      }
    }
}

// ---- MFMA GEMM 2: out = A(bf16) @ [Wmu|Wlv] + [bmu|blv], split store ----
__global__ __launch_bounds__(256) void k_gemm2(const ushort* __restrict__ A,
                                               const float* __restrict__ Wmu,
                                               const float* __restrict__ bmu,
                                               const float* __restrict__ Wlv,
                                               const float* __restrict__ blv,
                                               float* __restrict__ out) {
  __shared__ ushort Wt[FF * FF];  // Wt[c][k]: c<64 from Wmu, c>=64 from Wlv
  __shared__ float sb[FF];
  for (int i = threadIdx.x; i < FF * FF; i += 256) {
    int k = i >> 7, c = i & 127;
    float v = (c < OO) ? Wmu[k * OO + c] : Wlv[k * OO + (c - OO)];
    Wt[wt_idx(c, k)] = (ushort)f2bf(v);
  }
  if (threadIdx.x < FF)
    sb[threadIdx.x] = (threadIdx.x < OO) ? bmu[threadIdx.x] : blv[threadIdx.x - OO];
  __syncthreads();
  int l = threadIdx.x & 63, wv = threadIdx.x >> 6;
  int rbase = blockIdx.x * 128 + wv * 32;
  int lr = l & 15, lk = (l >> 4) << 3;
  f32x4 acc[2][8] = {};
#pragma unroll
  for (int kb = 0; kb < 4; ++kb) {
    int kk = kb * 32 + lk;
    short8 a[2];
#pragma unroll
    for (int rt = 0; rt < 2; ++rt) {
      int row = min(rbase + rt * 16 + lr, NN - 1);
      a[rt] = *(const short8*)(A + (size_t)row * FF + kk);
    }
#pragma unroll
    for (int ct = 0; ct < 8; ++ct) {
      int c = ct * 16 + lr;
      short8 b = *(const short8*)&Wt[wt_idx(c, kk)];
      acc[0][ct] = __builtin_amdgcn_mfma_f32_16x16x32_bf16(a[0], b, acc[0][ct], 0, 0, 0);
      acc[1][ct] = __builtin_amdgcn_mfma_f32_16x16x32_bf16(a[1], b, acc[1][ct], 0, 0, 0);
    }
  }
  int rl = (l >> 4) * 4;
#pragma unroll
  for (int rt = 0; rt < 2; ++rt)
#pragma unroll
    for (int reg = 0; reg < 4; ++reg) {
      int row = rbase + rt * 16 + rl + reg;
      if (row < NN) {
#pragma unroll
        for (int ct = 0; ct < 8; ++ct) {
          int c = ct * 16 + lr;
          float v = acc[rt][ct][reg] + sb[c];
          if (ct < 4) out[(size_t)row * OO + c] = v;                            // mu
          else out[(size_t)NN * OO + (size_t)row * OO + (c - OO)] = v;          // logvar
        }
      }
    }
}

// one wave per node, bf16 features, 8 outstanding row-loads per iter
// LN=1: fused bias+ReLU+LayerNorm epilogue (conv1); LN=0: raw write (conv2)
template <int LN>
__global__ __launch_bounds__(256) void k_gather(const int* __restrict__ rowptr,
                                                const int2* __restrict__ cw,
                                                const float* __restrict__ dis,
                                                const ushort* __restrict__ feat,
                                                const float* __restrict__ b1,
                                                const float* __restrict__ gamma,
                                                const float* __restrict__ beta,
                                                ushort* __restrict__ outp) {
  int node = blockIdx.x * 4 + (threadIdx.x >> 6);
  if (node >= NN) return;
  int lane = threadIdx.x & 63;
  float di = dis[node];
  float sw = di * di;
  uint sv = ((const uint*)(feat + ((size_t)node << 7)))[lane];
  float ax = sw * bflo(sv), ay = sw * bfhi(sv);
  int e = rowptr[node], end = rowptr[node + 1];
  for (; e + 7 < end; e += 8) {
    int2 c[8];
    uint v[8];
#pragma unroll
    for (int j = 0; j < 8; ++j) c[j] = cw[e + j];
#pragma unroll
    for (int j = 0; j < 8; ++j) v[j] = ((const uint*)(feat + ((size_t)c[j].x << 7)))[lane];
#pragma unroll
    for (int j = 0; j < 8; ++j) {
      float wj = __int_as_float(c[j].y);
      ax = fmaf(wj, bflo(v[j]), ax); ay = fmaf(wj, bfhi(v[j]), ay);
    }
  }
  if (e + 3 < end) {
    int2 c[4];
    uint v[4];
#pragma unroll
    for (int j = 0; j < 4; ++j) c[j] = cw[e + j];
#pragma unroll
    for (int j = 0; j < 4; ++j) v[j] = ((const uint*)(feat + ((size_t)c[j].x << 7)))[lane];
#pragma unroll
    for (int j = 0; j < 4; ++j) {
      float wj = __int_as_float(c[j].y);
      ax = fmaf(wj, bflo(v[j]), ax); ay = fmaf(wj, bfhi(v[j]), ay);
    }
    e += 4;
  }
  for (; e < end; ++e) {
    int2 c0 = cw[e];
    uint v0 = ((const uint*)(feat + ((size_t)c0.x << 7)))[lane];
    float w0 = __int_as_float(c0.y);
    ax = fmaf(w0, bflo(v0), ax); ay = fmaf(w0, bfhi(v0), ay);
  }
  float ox, oy;
  if (LN) {
    float b0 = b1[2 * lane], b1v = b1[2 * lane + 1];
    float a0 = fmaxf(ax + b0, 0.f);
    float a1 = fmaxf(ay + b1v, 0.f);
    float s = a0 + a1, sq = a0 * a0 + a1 * a1;
#pragma unroll
    for (int m = 1; m < 64; m <<= 1) {
      s += __shfl_xor(s, m);
      sq += __shfl_xor(sq, m);
    }
    float mean = s * (1.f / 128.f);
    float var = sq * (1.f / 128.f) - mean * mean;
    float rstd = rsqrtf(var + EPSF);
    float g0 = gamma[2 * lane], g1 = gamma[2 * lane + 1];
    float be0 = beta[2 * lane], be1 = beta[2 * lane + 1];
    ox = (a0 - mean) * rstd * g0 + be0;
    oy = (a1 - mean) * rstd * g1 + be1;
  } else {
    ox = ax; oy = ay;
  }
  ((uint*)(outp + ((size_t)node << 7)))[lane] = pack2(ox, oy);
}

extern "C" void kernel_launch(void* const* d_in, const int* in_sizes, int n_in,
                              void* d_out, int out_size, void* d_ws, size_t ws_size,
                              hipStream_t stream) {
  const float* x     = (const float*)d_in[0];
  const void*  ei    = d_in[1];
  const float* W1    = (const float*)d_in[2];
  const float* b1    = (const float*)d_in[3];
  const float* gamma = (const float*)d_in[4];
  const float* beta  = (const float*)d_in[5];
  const float* Wmu   = (const float*)d_in[6];
  const float* bmu   = (const float*)d_in[7];
  const float* Wlv   = (const float*)d_in[8];
  const float* blv   = (const float*)d_in[9];
  float* out = (float*)d_out;

  // workspace (4B words):
  // [flag 64][cnt N][rowptr N+16][dis N][bsum 256][boff 256][rank E]
  // [cw int2 E][t bf16 N*128][h bf16 N*128][t2 bf16 N*128]   ~48.6 MB
  int*   flag   = (int*)d_ws;
  int*   cnt    = flag + 64;
  int*   rowptr = cnt + NN;
  float* dis    = (float*)(rowptr + (NN + 16));
  int*   bsum   = (int*)(dis + NN);
  int*   boff   = bsum + 256;
  int*   rank   = boff + 256;
  size_t off32  = (size_t)(64 + NN + (NN + 16) + NN + 256 + 256 + EE);
  off32 = (off32 + 63) & ~(size_t)63;
  int2*  cw     = (int2*)((int*)d_ws + off32);
  ushort* t  = (ushort*)(cw + EE);
  ushort* h  = t + (size_t)NN * FF;
  ushort* t2 = h + (size_t)NN * FF;

  k_detect<<<1, 64, 0, stream>>>(ei, flag);
  k_cnt_init<<<(NN + 255) / 256, 256, 0, stream>>>(cnt);
  k_deg_rank<<<EBLK, 256, 0, stream>>>(ei, flag, cnt, rank);
  k_dis<<<(NN + 255) / 256, 256, 0, stream>>>(cnt, dis);
  k_scan_part<<<SCB, 256, 0, stream>>>(cnt, bsum);
  k_scan_tops<<<1, 256, 0, stream>>>(bsum, boff, rowptr);
  k_scan_write<<<SCB, 256, 0, stream>>>(cnt, boff, rowptr);
  k_scatter<<<EBLK, 256, 0, stream>>>(ei, flag, dis, rowptr, rank, cw);

  k_gemm1<<<GBLK, 256, 0, stream>>>(x, W1, t);
  k_gather<1><<<(NN + 3) / 4, 256, 0, stream>>>(rowptr, cw, dis, t, b1, gamma, beta, h);
  k_gather<0><<<(NN + 3) / 4, 256, 0, stream>>>(rowptr, cw, dis, h, b1, gamma, beta, t2);
  k_gemm2<<<GBLK, 256, 0, stream>>>(t2, Wmu, bmu, Wlv, blv, out);
}